// Round 9
// baseline (206.209 us; speedup 1.0000x reference)
//
#include <hip/hip_runtime.h>

#define BB 4
#define HH 480
#define WW 640
#define NPIX (BB * HH * WW)

// ---------- f64 helpers (fixup kernel) ----------
__device__ __forceinline__ double det3d(double a, double b, double c,
                                        double d, double e, double f,
                                        double g, double h, double i) {
    return a * (e * i - f * h) - b * (d * i - f * g) + c * (d * h - e * g);
}
__device__ __forceinline__ double sdet3d(double a, double b, double c,
                                         double e, double f, double i) {
    return a * (e * i - f * f) + b * (2.0 * c * f - b * i) - c * c * e;
}
__device__ __forceinline__ double crcp(double d) {
    return (double)__builtin_amdgcn_rcpf((float)d);  // scale-invariant / self-correcting uses
}
// ---------- f32 helpers (main kernel) ----------
__device__ __forceinline__ float det3f(float a, float b, float c,
                                       float d, float e, float f,
                                       float g, float h, float i) {
    return a * (e * i - f * h) - b * (d * i - f * g) + c * (d * h - e * g);
}
__device__ __forceinline__ float sdet3f(float a, float b, float c,
                                        float e, float f, float i) {
    return a * (e * i - f * f) + b * (2.0f * c * f - b * i) - c * c * e;
}

// Shared: branch-free clamped 3x3 stencil load + f32 Gram (reference precision).
__device__ __forceinline__ void load_gram(const float* __restrict__ pts, int x, int y, int b,
                                          float& sxx, float& sxy, float& sxz, float& sx,
                                          float& syy, float& syz, float& sy,
                                          float& szz, float& sz, float& cnt,
                                          float& cx, float& cy, float& cz) {
    const size_t HW = (size_t)HH * WW;
    const float* xs = pts + ((size_t)b * 3 + 0) * HW;
    const float* ys = pts + ((size_t)b * 3 + 1) * HW;
    const float* zs = pts + ((size_t)b * 3 + 2) * HW;
    int row[3], col[3];
    bool rin[3], cin[3];
#pragma unroll
    for (int k = 0; k < 3; ++k) {
        int yy = y + k - 1, xx = x + k - 1;
        rin[k] = (unsigned)yy < HH;
        cin[k] = (unsigned)xx < WW;
        row[k] = min(max(yy, 0), HH - 1) * WW;
        col[k] = min(max(xx, 0), WW - 1);
    }
    float px[9], py[9], pz[9];
    bool inb[9];
#pragma unroll
    for (int i = 0; i < 9; ++i) {
        int r = i / 3, c = i % 3;
        int o = row[r] + col[c];
        inb[i] = rin[r] & cin[c];
        pz[i] = zs[o];
        px[i] = xs[o];
        py[i] = ys[o];
    }
    sxx = sxy = sxz = sx = syy = syz = sy = szz = sz = cnt = 0.f;
#pragma unroll
    for (int i = 0; i < 9; ++i) {
        float w = (inb[i] && pz[i] > 0.0f && pz[i] < 10.0f) ? 1.0f : 0.0f;
        float qx = px[i] * w, qy = py[i] * w, qz = pz[i] * w;
        sxx += qx * px[i]; sxy += qx * py[i]; sxz += qx * pz[i]; sx += qx;
        syy += qy * py[i]; syz += qy * pz[i]; sy += qy;
        szz += qz * pz[i]; sz += qz;
        cnt += w;
    }
    cx = px[4]; cy = py[4]; cz = pz[4];
}

__device__ __forceinline__ void finish_store(float* __restrict__ out, int x, int y, int b,
                                             float fx, float fy, float fz,
                                             float cx, float cy, float cz, float cnt) {
    const size_t HW = (size_t)HH * WW;
    float nd = fx * fx + fy * fy + fz * fz;
    float inv = __builtin_amdgcn_rsqf(fmaxf(nd, 1e-30f));
    float nx = fx * inv, ny = fy * inv, nz = fz * inv;
    float dot = nx * cx + ny * cy + nz * cz;
    float sgn = (dot > 0.0f) ? 1.0f : ((dot < 0.0f) ? -1.0f : 0.0f);
    nx *= sgn; ny *= sgn; nz *= sgn;
    int o = y * WW + x;
    out[((size_t)b * 3 + 0) * HW + o] = nx;
    out[((size_t)b * 3 + 1) * HW + o] = ny;
    out[((size_t)b * 3 + 2) * HW + o] = nz;
    bool cvalid = (cz > 0.0f && cz < 10.0f);
    bool m = cvalid && (cnt >= 4.0f) && (nx * nx + ny * ny + nz * nz > 0.25f);
    out[(size_t)BB * 3 * HW + (size_t)b * HW + o] = m ? 1.0f : 0.0f;
}

// ================= main kernel: pure f32 + flag compaction =================
__global__ __launch_bounds__(256) void d2n_main(const float* __restrict__ pts,
                                                float* __restrict__ out,
                                                int* __restrict__ wslist, int cap) {
    int idx = blockIdx.x * 256 + threadIdx.x;
    if (idx >= NPIX) return;
    int x = idx % WW;
    int t1 = idx / WW;
    int y = t1 % HH;
    int b = t1 / HH;

    float sxx, sxy, sxz, sx, syy, syz, sy, szz, sz, cnt, cx, cy, cz;
    load_gram(pts, x, y, b, sxx, sxy, sxz, sx, syy, syz, sy, szz, sz, cnt, cx, cy, cz);

    float trf = sxx + syy + szz + cnt;
    float itf = __builtin_amdgcn_rcpf(trf);
    float f00 = sxx * itf, f01 = sxy * itf, f02 = sxz * itf, f03 = sx * itf;
    float f11 = syy * itf, f12 = syz * itf, f13 = sy * itf;
    float f22 = szz * itf, f23 = sz * itf, f33 = cnt * itf;

    float e1f = f00 + f11 + f22 + f33;
    float e2f = (f00 * f11 - f01 * f01) + (f00 * f22 - f02 * f02) +
                (f00 * f33 - f03 * f03) + (f11 * f22 - f12 * f12) +
                (f11 * f33 - f13 * f13) + (f22 * f33 - f23 * f23);
    float Q0 = sdet3f(f11, f12, f13, f22, f23, f33);
    float Q1 = sdet3f(f00, f02, f03, f22, f23, f33);
    float Q2 = sdet3f(f00, f01, f03, f11, f13, f33);
    float Q3 = sdet3f(f00, f01, f02, f11, f12, f22);
    float e3f = Q0 + Q1 + Q2 + Q3;
    float e4f = f00 * Q0
              - f01 * det3f(f01, f12, f13, f02, f22, f23, f03, f23, f33)
              + f02 * det3f(f01, f11, f13, f02, f12, f23, f03, f13, f33)
              - f03 * det3f(f01, f11, f12, f02, f12, f22, f03, f13, f23);

    float t31f = 3.0f * e1f, t22f = 2.0f * e2f;
    float lf = 0.0f;
#pragma unroll
    for (int itn = 0; itn < 10; ++itn) {
        float p  = (((lf - e1f) * lf + e2f) * lf - e3f) * lf + e4f;
        float dp = ((4.0f * lf - t31f) * lf + t22f) * lf - e3f;
        dp = fminf(dp, -1e-30f);
        lf = lf - p * __builtin_amdgcn_rcpf(dp);
        lf = fminf(fmaxf(lf, 0.0f), 0.26f);
    }
    // gap sensor: -dp(lam1) = prod_{k>1}(mu_k - mu_1) = c. Typical c ~ 2e-4 here
    // (mu ~ {0.006, 0.03, 0.03, 0.93} after trace scaling). Flag c < 2e-5.
    float dpf = ((4.0f * lf - t31f) * lf + t22f) * lf - e3f;

    float g0 = f00 - lf, g1 = f11 - lf, g2 = f22 - lf, g3 = f33 - lf;
    float B00 =  sdet3f(g1, f12, f13, g2, f23, g3);
    float B11 =  sdet3f(g0, f02, f03, g2, f23, g3);
    float B22 =  sdet3f(g0, f01, f03, g1, f13, g3);
    float B33 =  sdet3f(g0, f01, f02, g1, f12, g2);
    float B01 = -det3f(f01, f12, f13, f02, g2, f23, f03, f23, g3);
    float B02 =  det3f(f01, g1, f13, f02, f12, f23, f03, f13, g3);
    float B03 = -det3f(f01, g1, f12, f02, f12, g2, f03, f13, f23);
    float B12 = -det3f(g0, f01, f03, f02, f12, f23, f03, f13, g3);
    float B13 =  det3f(g0, f01, f02, f02, f12, g2, f03, f13, f23);
    float B23 = -det3f(g0, f01, f02, f01, g1, f12, f03, f13, f23);

    float bestf = fabsf(B00);
    float fx = B00, fy = B01, fz = B02;
    float b1a = fabsf(B11);
    if (b1a > bestf) { bestf = b1a; fx = B01; fy = B11; fz = B12; }
    float b2a = fabsf(B22);
    if (b2a > bestf) { bestf = b2a; fx = B02; fy = B12; fz = B22; }
    float b3a = fabsf(B33);
    if (b3a > bestf) { bestf = b3a; fx = B03; fy = B13; fz = B23; }

    float ndf = fx * fx + fy * fy + fz * fz;

    // NaN-safe flag (true on NaN): small gap product, clamp runaway, degenerate col
    bool flag = !(dpf < -2e-5f) || (lf > 0.2599f) || !(ndf > 1e-12f);
    if (flag) {
        int slot = atomicAdd(wslist, 1);
        if (slot < cap) wslist[1 + slot] = idx;
    }

    finish_store(out, x, y, b, fx, fy, fz, cx, cy, cz, cnt);
}

// ================= fixup kernel: R4-proven f64 pipeline over the list =================
__global__ __launch_bounds__(256) void d2n_fixup(const float* __restrict__ pts,
                                                 float* __restrict__ out,
                                                 const int* __restrict__ wslist, int cap) {
    int count = min(wslist[0], cap);
    for (int i = blockIdx.x * 256 + threadIdx.x; i < count; i += gridDim.x * 256) {
        int idx = wslist[1 + i];
        int x = idx % WW;
        int t1 = idx / WW;
        int y = t1 % HH;
        int b = t1 / HH;

        float sxx, sxy, sxz, sx, syy, syz, sy, szz, sz, cnt, cx, cy, cz;
        load_gram(pts, x, y, b, sxx, sxy, sxz, sx, syy, syz, sy, szz, sz, cnt, cx, cy, cz);

        double tr = (double)sxx + (double)syy + (double)szz + (double)cnt;
        double it = crcp(tr);
        double m00 = sxx * it, m01 = sxy * it, m02 = sxz * it, m03 = sx * it;
        double m11 = syy * it, m12 = syz * it, m13 = sy * it;
        double m22 = szz * it, m23 = sz * it, m33 = cnt * it;

        double e1 = m00 + m11 + m22 + m33;
        double e2 = (m00 * m11 - m01 * m01) + (m00 * m22 - m02 * m02) +
                    (m00 * m33 - m03 * m03) + (m11 * m22 - m12 * m12) +
                    (m11 * m33 - m13 * m13) + (m22 * m33 - m23 * m23);
        double P0 = sdet3d(m11, m12, m13, m22, m23, m33);
        double P1 = sdet3d(m00, m02, m03, m22, m23, m33);
        double P2 = sdet3d(m00, m01, m03, m11, m13, m33);
        double P3 = sdet3d(m00, m01, m02, m11, m12, m22);
        double e3 = P0 + P1 + P2 + P3;
        double e4 = m00 * P0
                  - m01 * det3d(m01, m12, m13, m02, m22, m23, m03, m23, m33)
                  + m02 * det3d(m01, m11, m13, m02, m12, m23, m03, m13, m33)
                  - m03 * det3d(m01, m11, m12, m02, m12, m22, m03, m13, m23);

        double t31 = 3.0 * e1, t22 = 2.0 * e2;
        double lam = 0.0;
#pragma unroll
        for (int itn = 0; itn < 14; ++itn) {
            double p  = (((lam - e1) * lam + e2) * lam - e3) * lam + e4;
            double dp = ((4.0 * lam - t31) * lam + t22) * lam - e3;
            dp = fmin(dp, -1e-30);
            lam = lam - p * crcp(dp);
            lam = fmin(fmax(lam, 0.0), 0.26);
        }

        double d0 = m00 - lam, d1 = m11 - lam, d2 = m22 - lam, d3 = m33 - lam;
        double C00 =  sdet3d(d1, m12, m13, d2, m23, d3);
        double C11 =  sdet3d(d0, m02, m03, d2, m23, d3);
        double C22 =  sdet3d(d0, m01, m03, d1, m13, d3);
        double C33 =  sdet3d(d0, m01, m02, d1, m12, d2);
        double C01 = -det3d(m01, m12, m13, m02, d2, m23, m03, m23, d3);
        double C02 =  det3d(m01, d1, m13, m02, m12, m23, m03, m13, d3);
        double C03 = -det3d(m01, d1, m12, m02, m12, d2, m03, m13, m23);
        double C12 = -det3d(d0, m01, m03, m02, m12, m23, m03, m13, d3);
        double C13 =  det3d(d0, m01, m02, m02, m12, d2, m03, m13, m23);
        double C23 = -det3d(d0, m01, m02, m01, d1, m12, m03, m13, m23);

        double best = fabs(C00);
        double vx = C00, vy = C01, vz = C02, vd = C00;
        double a1 = fabs(C11);
        if (a1 > best) { best = a1; vx = C01; vy = C11; vz = C12; vd = C11; }
        double a2 = fabs(C22);
        if (a2 > best) { best = a2; vx = C02; vy = C12; vz = C22; vd = C22; }
        double a3 = fabs(C33);
        if (a3 > best) { best = a3; vx = C03; vy = C13; vz = C23; vd = C33; }

        double sc = crcp(vd);  // uniform column scale: cancels in normalization
        float fx = (float)(vx * sc), fy = (float)(vy * sc), fz = (float)(vz * sc);

        finish_store(out, x, y, b, fx, fy, fz, cx, cy, cz, cnt);
    }
}

extern "C" void kernel_launch(void* const* d_in, const int* in_sizes, int n_in,
                              void* d_out, int out_size, void* d_ws, size_t ws_size,
                              hipStream_t stream) {
    const float* pts = (const float*)d_in[0];
    float* out = (float*)d_out;
    int* wslist = (int*)d_ws;
    int cap = (int)((ws_size / 4 > (size_t)(NPIX + 1)) ? NPIX : (int)(ws_size / 4) - 1);

    hipMemsetAsync(wslist, 0, 4, stream);  // zero the append counter
    d2n_main<<<(NPIX + 255) / 256, 256, 0, stream>>>(pts, out, wslist, cap);
    d2n_fixup<<<64, 256, 0, stream>>>(pts, out, wslist, cap);
}

// Round 10
// 204.640 us; speedup vs baseline: 1.0077x; 1.0077x over previous
//
#include <hip/hip_runtime.h>

#define BB 4
#define HH 480
#define WW 640
#define NPIX (BB * HH * WW)

// ---------- f64 helpers (fixup kernel) ----------
__device__ __forceinline__ double det3d(double a, double b, double c,
                                        double d, double e, double f,
                                        double g, double h, double i) {
    return a * (e * i - f * h) - b * (d * i - f * g) + c * (d * h - e * g);
}
__device__ __forceinline__ double sdet3d(double a, double b, double c,
                                         double e, double f, double i) {
    return a * (e * i - f * f) + b * (2.0 * c * f - b * i) - c * c * e;
}
__device__ __forceinline__ double crcp(double d) {
    return (double)__builtin_amdgcn_rcpf((float)d);  // scale-invariant / self-correcting uses
}
// ---------- f32 helpers (main kernel) ----------
__device__ __forceinline__ float det3f(float a, float b, float c,
                                       float d, float e, float f,
                                       float g, float h, float i) {
    return a * (e * i - f * h) - b * (d * i - f * g) + c * (d * h - e * g);
}
__device__ __forceinline__ float sdet3f(float a, float b, float c,
                                        float e, float f, float i) {
    return a * (e * i - f * f) + b * (2.0f * c * f - b * i) - c * c * e;
}

// Shared: branch-free clamped 3x3 stencil load + f32 Gram (reference precision).
__device__ __forceinline__ void load_gram(const float* __restrict__ pts, int x, int y, int b,
                                          float& sxx, float& sxy, float& sxz, float& sx,
                                          float& syy, float& syz, float& sy,
                                          float& szz, float& sz, float& cnt,
                                          float& cx, float& cy, float& cz) {
    const size_t HW = (size_t)HH * WW;
    const float* xs = pts + ((size_t)b * 3 + 0) * HW;
    const float* ys = pts + ((size_t)b * 3 + 1) * HW;
    const float* zs = pts + ((size_t)b * 3 + 2) * HW;
    int row[3], col[3];
    bool rin[3], cin[3];
#pragma unroll
    for (int k = 0; k < 3; ++k) {
        int yy = y + k - 1, xx = x + k - 1;
        rin[k] = (unsigned)yy < HH;
        cin[k] = (unsigned)xx < WW;
        row[k] = min(max(yy, 0), HH - 1) * WW;
        col[k] = min(max(xx, 0), WW - 1);
    }
    float px[9], py[9], pz[9];
    bool inb[9];
#pragma unroll
    for (int i = 0; i < 9; ++i) {
        int r = i / 3, c = i % 3;
        int o = row[r] + col[c];
        inb[i] = rin[r] & cin[c];
        pz[i] = zs[o];
        px[i] = xs[o];
        py[i] = ys[o];
    }
    sxx = sxy = sxz = sx = syy = syz = sy = szz = sz = cnt = 0.f;
#pragma unroll
    for (int i = 0; i < 9; ++i) {
        float w = (inb[i] && pz[i] > 0.0f && pz[i] < 10.0f) ? 1.0f : 0.0f;
        float qx = px[i] * w, qy = py[i] * w, qz = pz[i] * w;
        sxx += qx * px[i]; sxy += qx * py[i]; sxz += qx * pz[i]; sx += qx;
        syy += qy * py[i]; syz += qy * pz[i]; sy += qy;
        szz += qz * pz[i]; sz += qz;
        cnt += w;
    }
    cx = px[4]; cy = py[4]; cz = pz[4];
}

__device__ __forceinline__ void finish_store(float* __restrict__ out, int x, int y, int b,
                                             float fx, float fy, float fz,
                                             float cx, float cy, float cz, float cnt) {
    const size_t HW = (size_t)HH * WW;
    float nd = fx * fx + fy * fy + fz * fz;
    float inv = __builtin_amdgcn_rsqf(fmaxf(nd, 1e-30f));
    float nx = fx * inv, ny = fy * inv, nz = fz * inv;
    float dot = nx * cx + ny * cy + nz * cz;
    float sgn = (dot > 0.0f) ? 1.0f : ((dot < 0.0f) ? -1.0f : 0.0f);
    nx *= sgn; ny *= sgn; nz *= sgn;
    int o = y * WW + x;
    out[((size_t)b * 3 + 0) * HW + o] = nx;
    out[((size_t)b * 3 + 1) * HW + o] = ny;
    out[((size_t)b * 3 + 2) * HW + o] = nz;
    bool cvalid = (cz > 0.0f && cz < 10.0f);
    bool m = cvalid && (cnt >= 4.0f) && (nx * nx + ny * ny + nz * nz > 0.25f);
    out[(size_t)BB * 3 * HW + (size_t)b * HW + o] = m ? 1.0f : 0.0f;
}

// ================= main kernel: pure f32 + wave-aggregated flag compaction =================
// __launch_bounds__(256, 4): VGPR budget <=128. R8's heuristic chose 32 VGPR ->
// scratch spills -> VALUBusy 14.6%, 129 us. Below 64 VGPR there is NO occupancy
// gain (8 waves/SIMD is the hw max), so a tight cap is pure loss.
__global__ __launch_bounds__(256, 4) void d2n_main(const float* __restrict__ pts,
                                                   float* __restrict__ out,
                                                   int* __restrict__ wslist, int cap) {
    int idx = blockIdx.x * 256 + threadIdx.x;
    if (idx >= NPIX) return;
    int x = idx % WW;
    int t1 = idx / WW;
    int y = t1 % HH;
    int b = t1 / HH;

    float sxx, sxy, sxz, sx, syy, syz, sy, szz, sz, cnt, cx, cy, cz;
    load_gram(pts, x, y, b, sxx, sxy, sxz, sx, syy, syz, sy, szz, sz, cnt, cx, cy, cz);

    float trf = sxx + syy + szz + cnt;
    float itf = __builtin_amdgcn_rcpf(trf);
    float f00 = sxx * itf, f01 = sxy * itf, f02 = sxz * itf, f03 = sx * itf;
    float f11 = syy * itf, f12 = syz * itf, f13 = sy * itf;
    float f22 = szz * itf, f23 = sz * itf, f33 = cnt * itf;

    float e1f = f00 + f11 + f22 + f33;
    float e2f = (f00 * f11 - f01 * f01) + (f00 * f22 - f02 * f02) +
                (f00 * f33 - f03 * f03) + (f11 * f22 - f12 * f12) +
                (f11 * f33 - f13 * f13) + (f22 * f33 - f23 * f23);
    float Q0 = sdet3f(f11, f12, f13, f22, f23, f33);
    float Q1 = sdet3f(f00, f02, f03, f22, f23, f33);
    float Q2 = sdet3f(f00, f01, f03, f11, f13, f33);
    float Q3 = sdet3f(f00, f01, f02, f11, f12, f22);
    float e3f = Q0 + Q1 + Q2 + Q3;
    float e4f = f00 * Q0
              - f01 * det3f(f01, f12, f13, f02, f22, f23, f03, f23, f33)
              + f02 * det3f(f01, f11, f13, f02, f12, f23, f03, f13, f33)
              - f03 * det3f(f01, f11, f12, f02, f12, f22, f03, f13, f23);

    float t31f = 3.0f * e1f, t22f = 2.0f * e2f;
    float lf = 0.0f;
#pragma unroll
    for (int itn = 0; itn < 10; ++itn) {
        float p  = (((lf - e1f) * lf + e2f) * lf - e3f) * lf + e4f;
        float dp = ((4.0f * lf - t31f) * lf + t22f) * lf - e3f;
        dp = fminf(dp, -1e-30f);
        lf = lf - p * __builtin_amdgcn_rcpf(dp);
        lf = fminf(fmaxf(lf, 0.0f), 0.26f);
    }
    // gap sensor: -dp(lam1) = prod_{k>1}(mu_k - mu_1) = c. Typical c ~ 2e-4.
    float dpf = ((4.0f * lf - t31f) * lf + t22f) * lf - e3f;

    float g0 = f00 - lf, g1 = f11 - lf, g2 = f22 - lf, g3 = f33 - lf;
    float B00 =  sdet3f(g1, f12, f13, g2, f23, g3);
    float B11 =  sdet3f(g0, f02, f03, g2, f23, g3);
    float B22 =  sdet3f(g0, f01, f03, g1, f13, g3);
    float B33 =  sdet3f(g0, f01, f02, g1, f12, g2);
    float B01 = -det3f(f01, f12, f13, f02, g2, f23, f03, f23, g3);
    float B02 =  det3f(f01, g1, f13, f02, f12, f23, f03, f13, g3);
    float B03 = -det3f(f01, g1, f12, f02, f12, g2, f03, f13, f23);
    float B12 = -det3f(g0, f01, f03, f02, f12, f23, f03, f13, g3);
    float B13 =  det3f(g0, f01, f02, f02, f12, g2, f03, f13, f23);
    float B23 = -det3f(g0, f01, f02, f01, g1, f12, f03, f13, f23);

    float bestf = fabsf(B00);
    float fx = B00, fy = B01, fz = B02;
    float b1a = fabsf(B11);
    if (b1a > bestf) { bestf = b1a; fx = B01; fy = B11; fz = B12; }
    float b2a = fabsf(B22);
    if (b2a > bestf) { bestf = b2a; fx = B02; fy = B12; fz = B22; }
    float b3a = fabsf(B33);
    if (b3a > bestf) { bestf = b3a; fx = B03; fy = B13; fz = B23; }

    float ndf = fx * fx + fy * fy + fz * fz;

    // NaN-safe flag (true on NaN): small gap product, clamp runaway, degenerate col
    bool flag = !(dpf < -2e-5f) || (lf > 0.2599f) || !(ndf > 1e-12f);

    // wave-aggregated append: one atomic per wave (leader), popcount prefix per lane
    unsigned long long mask = __ballot(flag);
    if (mask != 0ull) {
        int lane = threadIdx.x & 63;
        int leader = __ffsll((long long)mask) - 1;
        int base = 0;
        if (lane == leader) base = atomicAdd(wslist, __popcll(mask));
        base = __shfl(base, leader);
        if (flag) {
            int slot = base + __popcll(mask & ((1ull << lane) - 1ull));
            if (slot < cap) wslist[1 + slot] = idx;
        }
    }

    finish_store(out, x, y, b, fx, fy, fz, cx, cy, cz, cnt);
}

// ================= fixup kernel: R4-proven f64 pipeline over the list =================
__global__ __launch_bounds__(256) void d2n_fixup(const float* __restrict__ pts,
                                                 float* __restrict__ out,
                                                 const int* __restrict__ wslist, int cap) {
    int count = min(wslist[0], cap);
    for (int i = blockIdx.x * 256 + threadIdx.x; i < count; i += gridDim.x * 256) {
        int idx = wslist[1 + i];
        int x = idx % WW;
        int t1 = idx / WW;
        int y = t1 % HH;
        int b = t1 / HH;

        float sxx, sxy, sxz, sx, syy, syz, sy, szz, sz, cnt, cx, cy, cz;
        load_gram(pts, x, y, b, sxx, sxy, sxz, sx, syy, syz, sy, szz, sz, cnt, cx, cy, cz);

        double tr = (double)sxx + (double)syy + (double)szz + (double)cnt;
        double it = crcp(tr);
        double m00 = sxx * it, m01 = sxy * it, m02 = sxz * it, m03 = sx * it;
        double m11 = syy * it, m12 = syz * it, m13 = sy * it;
        double m22 = szz * it, m23 = sz * it, m33 = cnt * it;

        double e1 = m00 + m11 + m22 + m33;
        double e2 = (m00 * m11 - m01 * m01) + (m00 * m22 - m02 * m02) +
                    (m00 * m33 - m03 * m03) + (m11 * m22 - m12 * m12) +
                    (m11 * m33 - m13 * m13) + (m22 * m33 - m23 * m23);
        double P0 = sdet3d(m11, m12, m13, m22, m23, m33);
        double P1 = sdet3d(m00, m02, m03, m22, m23, m33);
        double P2 = sdet3d(m00, m01, m03, m11, m13, m33);
        double P3 = sdet3d(m00, m01, m02, m11, m12, m22);
        double e3 = P0 + P1 + P2 + P3;
        double e4 = m00 * P0
                  - m01 * det3d(m01, m12, m13, m02, m22, m23, m03, m23, m33)
                  + m02 * det3d(m01, m11, m13, m02, m12, m23, m03, m13, m33)
                  - m03 * det3d(m01, m11, m12, m02, m12, m22, m03, m13, m23);

        double t31 = 3.0 * e1, t22 = 2.0 * e2;
        double lam = 0.0;
#pragma unroll
        for (int itn = 0; itn < 14; ++itn) {
            double p  = (((lam - e1) * lam + e2) * lam - e3) * lam + e4;
            double dp = ((4.0 * lam - t31) * lam + t22) * lam - e3;
            dp = fmin(dp, -1e-30);
            lam = lam - p * crcp(dp);
            lam = fmin(fmax(lam, 0.0), 0.26);
        }

        double d0 = m00 - lam, d1 = m11 - lam, d2 = m22 - lam, d3 = m33 - lam;
        double C00 =  sdet3d(d1, m12, m13, d2, m23, d3);
        double C11 =  sdet3d(d0, m02, m03, d2, m23, d3);
        double C22 =  sdet3d(d0, m01, m03, d1, m13, d3);
        double C33 =  sdet3d(d0, m01, m02, d1, m12, d2);
        double C01 = -det3d(m01, m12, m13, m02, d2, m23, m03, m23, d3);
        double C02 =  det3d(m01, d1, m13, m02, m12, m23, m03, m13, d3);
        double C03 = -det3d(m01, d1, m12, m02, m12, d2, m03, m13, m23);
        double C12 = -det3d(d0, m01, m03, m02, m12, m23, m03, m13, d3);
        double C13 =  det3d(d0, m01, m02, m02, m12, d2, m03, m13, m23);
        double C23 = -det3d(d0, m01, m02, m01, d1, m12, m03, m13, m23);

        double best = fabs(C00);
        double vx = C00, vy = C01, vz = C02, vd = C00;
        double a1 = fabs(C11);
        if (a1 > best) { best = a1; vx = C01; vy = C11; vz = C12; vd = C11; }
        double a2 = fabs(C22);
        if (a2 > best) { best = a2; vx = C02; vy = C12; vz = C22; vd = C22; }
        double a3 = fabs(C33);
        if (a3 > best) { best = a3; vx = C03; vy = C13; vz = C23; vd = C33; }

        double sc = crcp(vd);  // uniform column scale: cancels in normalization
        float fx = (float)(vx * sc), fy = (float)(vy * sc), fz = (float)(vz * sc);

        finish_store(out, x, y, b, fx, fy, fz, cx, cy, cz, cnt);
    }
}

extern "C" void kernel_launch(void* const* d_in, const int* in_sizes, int n_in,
                              void* d_out, int out_size, void* d_ws, size_t ws_size,
                              hipStream_t stream) {
    const float* pts = (const float*)d_in[0];
    float* out = (float*)d_out;
    int* wslist = (int*)d_ws;
    int cap = (int)((ws_size / 4 > (size_t)(NPIX + 1)) ? NPIX : (int)(ws_size / 4) - 1);

    hipMemsetAsync(wslist, 0, 4, stream);  // zero the append counter
    d2n_main<<<(NPIX + 255) / 256, 256, 0, stream>>>(pts, out, wslist, cap);
    d2n_fixup<<<64, 256, 0, stream>>>(pts, out, wslist, cap);
}

// Round 11
// 93.699 us; speedup vs baseline: 2.2008x; 2.1840x over previous
//
#include <hip/hip_runtime.h>

#define BB 4
#define HH 480
#define WW 640

// ---------- f64 helpers (rare-path) ----------
__device__ __forceinline__ double det3d(double a, double b, double c,
                                        double d, double e, double f,
                                        double g, double h, double i) {
    return a * (e * i - f * h) - b * (d * i - f * g) + c * (d * h - e * g);
}
__device__ __forceinline__ double sdet3d(double a, double b, double c,
                                         double e, double f, double i) {
    return a * (e * i - f * f) + b * (2.0 * c * f - b * i) - c * c * e;
}
// cheap f64 reciprocal (f32 seed, ~1e-5 rel): scale-invariant/self-correcting uses only
__device__ __forceinline__ double crcp(double d) {
    return (double)__builtin_amdgcn_rcpf((float)d);
}
// ---------- f32 helpers (common path) ----------
__device__ __forceinline__ float det3f(float a, float b, float c,
                                       float d, float e, float f,
                                       float g, float h, float i) {
    return a * (e * i - f * h) - b * (d * i - f * g) + c * (d * h - e * g);
}
__device__ __forceinline__ float sdet3f(float a, float b, float c,
                                        float e, float f, float i) {
    return a * (e * i - f * f) + b * (2.0f * c * f - b * i) - c * c * e;
}

__global__ __launch_bounds__(256) void d2n_kernel(const float* __restrict__ pts,
                                                  float* __restrict__ out) {
    int idx = blockIdx.x * 256 + threadIdx.x;
    if (idx >= BB * HH * WW) return;
    int x = idx % WW;
    int t1 = idx / WW;
    int y = t1 % HH;
    int b = t1 / HH;

    const size_t HW = (size_t)HH * WW;
    const float* xs = pts + ((size_t)b * 3 + 0) * HW;
    const float* ys = pts + ((size_t)b * 3 + 1) * HW;
    const float* zs = pts + ((size_t)b * 3 + 2) * HW;

    // ---- Branch-free stencil (R5-proven): clamped addrs, 27 loads in flight ----
    int row[3], col[3];
    bool rin[3], cin[3];
#pragma unroll
    for (int k = 0; k < 3; ++k) {
        int yy = y + k - 1, xx = x + k - 1;
        rin[k] = (unsigned)yy < HH;
        cin[k] = (unsigned)xx < WW;
        row[k] = min(max(yy, 0), HH - 1) * WW;
        col[k] = min(max(xx, 0), WW - 1);
    }
    float px[9], py[9], pz[9];
    bool inb[9];
#pragma unroll
    for (int i = 0; i < 9; ++i) {
        int r = i / 3, c = i % 3;
        int o = row[r] + col[c];
        inb[i] = rin[r] & cin[c];
        pz[i] = zs[o];
        px[i] = xs[o];
        py[i] = ys[o];
    }

    // ---- Gram accumulation (f32, matches reference AtA precision) ----
    float sxx = 0.f, sxy = 0.f, sxz = 0.f, sx = 0.f;
    float syy = 0.f, syz = 0.f, sy = 0.f;
    float szz = 0.f, sz = 0.f, cnt = 0.f;
#pragma unroll
    for (int i = 0; i < 9; ++i) {
        float w = (inb[i] && pz[i] > 0.0f && pz[i] < 10.0f) ? 1.0f : 0.0f;
        float qx = px[i] * w, qy = py[i] * w, qz = pz[i] * w;
        sxx += qx * px[i]; sxy += qx * py[i]; sxz += qx * pz[i]; sx += qx;
        syy += qy * py[i]; syz += qy * pz[i]; sy += qy;
        szz += qz * pz[i]; sz += qz;
        cnt += w;
    }

    // ================= f32 fast path (all lanes) =================
    float trf = sxx + syy + szz + cnt;
    float itf = __builtin_amdgcn_rcpf(trf);
    float f00 = sxx * itf, f01 = sxy * itf, f02 = sxz * itf, f03 = sx * itf;
    float f11 = syy * itf, f12 = syz * itf, f13 = sy * itf;
    float f22 = szz * itf, f23 = sz * itf, f33 = cnt * itf;

    float e1f = f00 + f11 + f22 + f33;
    float e2f = (f00 * f11 - f01 * f01) + (f00 * f22 - f02 * f02) +
                (f00 * f33 - f03 * f03) + (f11 * f22 - f12 * f12) +
                (f11 * f33 - f13 * f13) + (f22 * f33 - f23 * f23);
    float Q0 = sdet3f(f11, f12, f13, f22, f23, f33);
    float Q1 = sdet3f(f00, f02, f03, f22, f23, f33);
    float Q2 = sdet3f(f00, f01, f03, f11, f13, f33);
    float Q3 = sdet3f(f00, f01, f02, f11, f12, f22);
    float e3f = Q0 + Q1 + Q2 + Q3;
    float e4f = f00 * Q0
              - f01 * det3f(f01, f12, f13, f02, f22, f23, f03, f23, f33)
              + f02 * det3f(f01, f11, f13, f02, f12, f23, f03, f13, f33)
              - f03 * det3f(f01, f11, f12, f02, f12, f22, f03, f13, f23);

    float t31f = 3.0f * e1f, t22f = 2.0f * e2f;
    float lf = 0.0f;
#pragma unroll
    for (int itn = 0; itn < 10; ++itn) {
        float p  = (((lf - e1f) * lf + e2f) * lf - e3f) * lf + e4f;
        float dp = ((4.0f * lf - t31f) * lf + t22f) * lf - e3f;
        dp = fminf(dp, -1e-30f);
        lf = lf - p * __builtin_amdgcn_rcpf(dp);
        lf = fminf(fmaxf(lf, 0.0f), 0.26f);
    }
    // gap sensor: dp(lf) = -prod_{k>1}(mu_k - mu_1) = -c. |c| small => f32 unsafe.
    float dpf = ((4.0f * lf - t31f) * lf + t22f) * lf - e3f;

    // f32 adjugate of (M - lf I)
    float g0 = f00 - lf, g1 = f11 - lf, g2 = f22 - lf, g3 = f33 - lf;
    float B00 =  sdet3f(g1, f12, f13, g2, f23, g3);
    float B11 =  sdet3f(g0, f02, f03, g2, f23, g3);
    float B22 =  sdet3f(g0, f01, f03, g1, f13, g3);
    float B33 =  sdet3f(g0, f01, f02, g1, f12, g2);
    float B01 = -det3f(f01, f12, f13, f02, g2, f23, f03, f23, g3);
    float B02 =  det3f(f01, g1, f13, f02, f12, f23, f03, f13, g3);
    float B03 = -det3f(f01, g1, f12, f02, f12, g2, f03, f13, f23);
    float B12 = -det3f(g0, f01, f03, f02, f12, f23, f03, f13, g3);
    float B13 =  det3f(g0, f01, f02, f02, f12, g2, f03, f13, f23);
    float B23 = -det3f(g0, f01, f02, f01, g1, f12, f03, f13, f23);

    float bestf = fabsf(B00);
    float fx = B00, fy = B01, fz = B02;
    float b1a = fabsf(B11);
    if (b1a > bestf) { bestf = b1a; fx = B01; fy = B11; fz = B12; }
    float b2a = fabsf(B22);
    if (b2a > bestf) { bestf = b2a; fx = B02; fy = B12; fz = B22; }
    float b3a = fabsf(B33);
    if (b3a > bestf) { bestf = b3a; fx = B03; fy = B13; fz = B23; }

    float ndf = fx * fx + fy * fy + fz * fz;

    // flag: small eigen-gap product, clamp-runaway, or degenerate column.
    // Threshold 2e-5 (typical c ~ 2e-4..5e-4; R7's 2e-4 flagged ~half of all
    // lanes -> every wave took the rescue). 2e-5 rescue set empirically
    // sufficient for the bf16-floor absmax (R8/R9). NaN-safe: !(x<y) true on NaN.
    bool flag = !(dpf < -2e-5f) || (lf > 0.2599f) || !(ndf > 1e-12f);

    // ================= f64 rescue path (rare waves) =================
    if (__any(flag)) {
        double tr = (double)sxx + (double)syy + (double)szz + (double)cnt;
        double it = crcp(tr);
        double m00 = sxx * it, m01 = sxy * it, m02 = sxz * it, m03 = sx * it;
        double m11 = syy * it, m12 = syz * it, m13 = sy * it;
        double m22 = szz * it, m23 = sz * it, m33 = cnt * it;

        double e1 = m00 + m11 + m22 + m33;
        double e2 = (m00 * m11 - m01 * m01) + (m00 * m22 - m02 * m02) +
                    (m00 * m33 - m03 * m03) + (m11 * m22 - m12 * m12) +
                    (m11 * m33 - m13 * m13) + (m22 * m33 - m23 * m23);
        double P0 = sdet3d(m11, m12, m13, m22, m23, m33);
        double P1 = sdet3d(m00, m02, m03, m22, m23, m33);
        double P2 = sdet3d(m00, m01, m03, m11, m13, m33);
        double P3 = sdet3d(m00, m01, m02, m11, m12, m22);
        double e3 = P0 + P1 + P2 + P3;
        double e4 = m00 * P0
                  - m01 * det3d(m01, m12, m13, m02, m22, m23, m03, m23, m33)
                  + m02 * det3d(m01, m11, m13, m02, m12, m23, m03, m13, m33)
                  - m03 * det3d(m01, m11, m12, m02, m12, m22, m03, m13, m23);

        // 14 f64 Newton iters from 0 (R4-proven for near-double roots)
        double t31 = 3.0 * e1, t22 = 2.0 * e2;
        double lam = 0.0;
#pragma unroll
        for (int itn = 0; itn < 14; ++itn) {
            double p  = (((lam - e1) * lam + e2) * lam - e3) * lam + e4;
            double dp = ((4.0 * lam - t31) * lam + t22) * lam - e3;
            dp = fmin(dp, -1e-30);
            lam = lam - p * crcp(dp);
            lam = fmin(fmax(lam, 0.0), 0.26);
        }

        double d0 = m00 - lam, d1 = m11 - lam, d2 = m22 - lam, d3 = m33 - lam;
        double C00 =  sdet3d(d1, m12, m13, d2, m23, d3);
        double C11 =  sdet3d(d0, m02, m03, d2, m23, d3);
        double C22 =  sdet3d(d0, m01, m03, d1, m13, d3);
        double C33 =  sdet3d(d0, m01, m02, d1, m12, d2);
        double C01 = -det3d(m01, m12, m13, m02, d2, m23, m03, m23, d3);
        double C02 =  det3d(m01, d1, m13, m02, m12, m23, m03, m13, d3);
        double C03 = -det3d(m01, d1, m12, m02, m12, d2, m03, m13, m23);
        double C12 = -det3d(d0, m01, m03, m02, m12, m23, m03, m13, d3);
        double C13 =  det3d(d0, m01, m02, m02, m12, d2, m03, m13, m23);
        double C23 = -det3d(d0, m01, m02, m01, d1, m12, m03, m13, m23);

        double best = fabs(C00);
        double vx = C00, vy = C01, vz = C02, vd = C00;
        double a1 = fabs(C11);
        if (a1 > best) { best = a1; vx = C01; vy = C11; vz = C12; vd = C11; }
        double a2 = fabs(C22);
        if (a2 > best) { best = a2; vx = C02; vy = C12; vz = C22; vd = C22; }
        double a3 = fabs(C33);
        if (a3 > best) { best = a3; vx = C03; vy = C13; vz = C23; vd = C33; }

        double sc = crcp(vd);  // uniform column scale: cancels in normalization
        float gx = (float)(vx * sc), gy = (float)(vy * sc), gz = (float)(vz * sc);

        // per-lane merge: flagged lanes take the f64 result
        fx = flag ? gx : fx;
        fy = flag ? gy : fy;
        fz = flag ? gz : fz;
        ndf = fx * fx + fy * fy + fz * fz;
    }

    // ---- Normalize, sign-flip by center point, mask, store ----
    float inv = __builtin_amdgcn_rsqf(fmaxf(ndf, 1e-30f));
    float nx = fx * inv, ny = fy * inv, nz = fz * inv;

    int o = y * WW + x;
    float cx = px[4], cy = py[4], cz = pz[4];
    float dot = nx * cx + ny * cy + nz * cz;
    float sgn = (dot > 0.0f) ? 1.0f : ((dot < 0.0f) ? -1.0f : 0.0f);
    nx *= sgn; ny *= sgn; nz *= sgn;

    out[((size_t)b * 3 + 0) * HW + o] = nx;
    out[((size_t)b * 3 + 1) * HW + o] = ny;
    out[((size_t)b * 3 + 2) * HW + o] = nz;

    bool cvalid = (cz > 0.0f && cz < 10.0f);
    bool m = cvalid && (cnt >= 4.0f) && (nx * nx + ny * ny + nz * nz > 0.25f);
    out[(size_t)BB * 3 * HW + (size_t)b * HW + o] = m ? 1.0f : 0.0f;
}

extern "C" void kernel_launch(void* const* d_in, const int* in_sizes, int n_in,
                              void* d_out, int out_size, void* d_ws, size_t ws_size,
                              hipStream_t stream) {
    const float* pts = (const float*)d_in[0];
    float* out = (float*)d_out;
    int total = BB * HH * WW;
    d2n_kernel<<<(total + 255) / 256, 256, 0, stream>>>(pts, out);
}